// Round 5
// baseline (873.834 us; speedup 1.0000x reference)
//
#include <hip/hip_runtime.h>

#define NLEVELS 16
#define BLOCK 256
#define PPT 2    // points per thread, pass 1

typedef float v4f __attribute__((ext_vector_type(4)));  // NT-store-compatible

struct HashParams {
    unsigned offs[NLEVELS + 1];
    unsigned hsize[NLEVELS];
    unsigned hash_bits;
    unsigned pow2_bits;
};

// Gather the (dx=0, dx=1) corner pair with 1 float4 + predicated float2.
// A = hashed/modded index of corner dx=0; B = index of corner dx=1 (used only
// when ix is odd). When ix is even, {A, A^1} = {A&~1, A|1} is a 16B-aligned
// pair (holds for &mask and %hs since every hs is even), so one float4 covers
// both corners.
__device__ __forceinline__ void gather_pair(const float2* __restrict__ tab,
                                            unsigned A, unsigned B, unsigned ix,
                                            float2& c0, float2& c1)
{
    const float4 q = *(const float4*)(tab + (A & ~1u));
    float2 g = make_float2(0.f, 0.f);
    if (ix & 1u) g = tab[B];                       // predicated, odd lanes only
    const float2 lo = make_float2(q.x, q.y);
    const float2 hi = make_float2(q.z, q.w);
    c0 = (A & 1u) ? hi : lo;
    const float2 other = (A & 1u) ? lo : hi;
    c1 = (ix & 1u) ? g : other;
}

// ---------------- pass 1: level-phased gather+interp -> level-major ws ------
__global__ void __launch_bounds__(BLOCK)
hashenc_pass1(const float* __restrict__ xyz,
              const float* __restrict__ emb,
              float2* __restrict__ ws,
              HashParams p, int np, int bpl_shift)
{
    const int l = blockIdx.x >> bpl_shift;
    const int chunk = blockIdx.x & ((1 << bpl_shift) - 1);
    const int tid = threadIdx.x;

    const unsigned hs = p.hsize[l];
    const float2* __restrict__ tab = (const float2*)emb + p.offs[l];
    const float scale = (float)((16u << l) - 1u);
    const bool do_hash = (p.hash_bits >> l) & 1u;
    const bool is_pow2 = (p.pow2_bits >> l) & 1u;
    float2* __restrict__ wl = ws + (size_t)l * np;

    const int base = chunk * (BLOCK * PPT) + tid;

#pragma unroll
    for (int s = 0; s < PPT; ++s) {
        const int pidx = base + s * BLOCK;
        const float x = xyz[pidx * 3 + 0];
        const float y = xyz[pidx * 3 + 1];
        const float z = xyz[pidx * 3 + 2];

        const float px = x * scale + 0.5f;
        const float py = y * scale + 0.5f;
        const float pz = z * scale + 0.5f;
        const float gx = floorf(px), gy = floorf(py), gz = floorf(pz);
        const float fx = px - gx, fy = py - gy, fz = pz - gz;
        const unsigned ix = (unsigned)gx, iy = (unsigned)gy, iz = (unsigned)gz;

        float2 e[8];
        if (do_hash) {
            const unsigned hy0 = iy * 2654435761u;
            const unsigned hz0 = iz * 805459861u;
            const unsigned hy1 = hy0 + 2654435761u;
            const unsigned hz1 = hz0 + 805459861u;
            const unsigned hyz[4] = {hy0 ^ hz0, hy1 ^ hz0, hy0 ^ hz1, hy1 ^ hz1};
            if (is_pow2) {
                const unsigned m = hs - 1u;
#pragma unroll
                for (int pr = 0; pr < 4; ++pr) {
                    const unsigned A = (ix ^ hyz[pr]) & m;
                    const unsigned B = ((ix + 1u) ^ hyz[pr]) & m;
                    gather_pair(tab, A, B, ix, e[2 * pr], e[2 * pr + 1]);
                }
            } else {
#pragma unroll
                for (int pr = 0; pr < 4; ++pr) {
                    const unsigned A = (ix ^ hyz[pr]) % hs;
                    const unsigned B = ((ix + 1u) ^ hyz[pr]) % hs;
                    gather_pair(tab, A, B, ix, e[2 * pr], e[2 * pr + 1]);
                }
            }
        } else {
            const unsigned stride = (16u << l) + 1u;
#pragma unroll
            for (int c = 0; c < 8; ++c) {
                const unsigned lin = (ix + (c & 1))
                                   + (iy + ((c >> 1) & 1)) * stride
                                   + (iz + ((c >> 2) & 1)) * stride * stride;
                e[c] = tab[lin % hs];
            }
        }

        const float wx[2] = {1.0f - fx, fx};
        const float wy[2] = {1.0f - fy, fy};
        const float wz[2] = {1.0f - fz, fz};
        float o0 = 0.0f, o1 = 0.0f;
#pragma unroll
        for (int c = 0; c < 8; ++c) {
            const float w = wx[c & 1] * wy[(c >> 1) & 1] * wz[(c >> 2) & 1];
            o0 = fmaf(w, e[c].x, o0);
            o1 = fmaf(w, e[c].y, o1);
        }
        wl[pidx] = make_float2(o0, o1);
    }
}

// ---------------- pass 2: register transpose ws[l][p][2] -> out[p][32] ------
// One point per thread: 16 coalesced float2 reads (all in flight), then the
// point's contiguous 128B written as 8 float4 NT stores (full-line writes).
__global__ void __launch_bounds__(BLOCK)
hashenc_pass2(const float2* __restrict__ ws, float* __restrict__ out, int np)
{
    const int pidx = blockIdx.x * BLOCK + threadIdx.x;
    float2 v[NLEVELS];
#pragma unroll
    for (int l = 0; l < NLEVELS; ++l)
        v[l] = ws[(size_t)l * np + pidx];

    v4f* __restrict__ o = (v4f*)(out + (size_t)pidx * 32);
#pragma unroll
    for (int k = 0; k < 8; ++k) {
        v4f q;
        q.x = v[2 * k].x;     q.y = v[2 * k].y;
        q.z = v[2 * k + 1].x; q.w = v[2 * k + 1].y;
        __builtin_nontemporal_store(q, o + k);
    }
}

// ---------------- fallback: single-pass kernel (ws too small) ---------------
__global__ void __launch_bounds__(BLOCK)
hashenc_fwd(const float* __restrict__ xyz,
            const float* __restrict__ emb,
            float* __restrict__ out,
            HashParams p)
{
    const int tid = threadIdx.x;
    const long b = (long)blockIdx.x * BLOCK + tid;
    __shared__ float lds[BLOCK * 33];

    const float x = xyz[b * 3 + 0];
    const float y = xyz[b * 3 + 1];
    const float z = xyz[b * 3 + 2];

#pragma unroll
    for (int l = 0; l < NLEVELS; ++l) {
        const float scale = (float)((16u << l) - 1u);
        const float px = x * scale + 0.5f;
        const float py = y * scale + 0.5f;
        const float pz = z * scale + 0.5f;
        const float gx = floorf(px), gy = floorf(py), gz = floorf(pz);
        const float fx = px - gx, fy = py - gy, fz = pz - gz;
        const unsigned ix = (unsigned)gx, iy = (unsigned)gy, iz = (unsigned)gz;
        const unsigned hs = p.hsize[l];
        const float2* __restrict__ tab = (const float2*)emb + p.offs[l];

        float2 e[8];
        if ((p.hash_bits >> l) & 1u) {
            const unsigned hy0 = iy * 2654435761u;
            const unsigned hz0 = iz * 805459861u;
            const unsigned hy1 = hy0 + 2654435761u;
            const unsigned hz1 = hz0 + 805459861u;
            const unsigned hyz[4] = {hy0 ^ hz0, hy1 ^ hz0, hy0 ^ hz1, hy1 ^ hz1};
            if ((p.pow2_bits >> l) & 1u) {
                const unsigned m = hs - 1u;
#pragma unroll
                for (int pr = 0; pr < 4; ++pr) {
                    const unsigned A = (ix ^ hyz[pr]) & m;
                    const unsigned B = ((ix + 1u) ^ hyz[pr]) & m;
                    gather_pair(tab, A, B, ix, e[2 * pr], e[2 * pr + 1]);
                }
            } else {
#pragma unroll
                for (int pr = 0; pr < 4; ++pr) {
                    const unsigned A = (ix ^ hyz[pr]) % hs;
                    const unsigned B = ((ix + 1u) ^ hyz[pr]) % hs;
                    gather_pair(tab, A, B, ix, e[2 * pr], e[2 * pr + 1]);
                }
            }
        } else {
            const unsigned stride = (16u << l) + 1u;
#pragma unroll
            for (int c = 0; c < 8; ++c) {
                const unsigned lin = (ix + (c & 1))
                                   + (iy + ((c >> 1) & 1)) * stride
                                   + (iz + ((c >> 2) & 1)) * stride * stride;
                e[c] = tab[lin % hs];
            }
        }

        const float wx[2] = {1.0f - fx, fx};
        const float wy[2] = {1.0f - fy, fy};
        const float wz[2] = {1.0f - fz, fz};
        float o0 = 0.0f, o1 = 0.0f;
#pragma unroll
        for (int c = 0; c < 8; ++c) {
            const float w = wx[c & 1] * wy[(c >> 1) & 1] * wz[(c >> 2) & 1];
            o0 = fmaf(w, e[c].x, o0);
            o1 = fmaf(w, e[c].y, o1);
        }
        lds[tid * 33 + l * 2 + 0] = o0;
        lds[tid * 33 + l * 2 + 1] = o1;
    }

    __syncthreads();
    float* __restrict__ ochunk = out + (long)blockIdx.x * (BLOCK * 32);
#pragma unroll
    for (int k = 0; k < 32; ++k) {
        const int flat = k * BLOCK + tid;
        const float v = lds[(flat >> 5) * 33 + (flat & 31)];
        __builtin_nontemporal_store(v, ochunk + flat);
    }
}

extern "C" void kernel_launch(void* const* d_in, const int* in_sizes, int n_in,
                              void* d_out, int out_size, void* d_ws, size_t ws_size,
                              hipStream_t stream) {
    const float* xyz = (const float*)d_in[0];
    const float* emb = (const float*)d_in[1];
    float* out = (float*)d_out;
    const int B = in_sizes[0] / 3;

    // Reproduce HashEncoder.__init__ offset arithmetic exactly.
    HashParams p;
    p.offs[0] = 0;
    unsigned hash_bits = 0, pow2_bits = 0;
    long off = 0;
    for (int i = 0; i < NLEVELS; ++i) {
        const long res = 16L << i;
        const long dense = (res + 1) * (res + 1) * (res + 1);
        long t = dense < (1L << 19) ? dense : (1L << 19);
        t = (t / 8) * 8;
        p.hsize[i] = (unsigned)t;
        off += t;
        p.offs[i + 1] = (unsigned)off;
        if (dense > t) hash_bits |= (1u << i);
        if ((t & (t - 1)) == 0) pow2_bits |= (1u << i);
    }
    p.hash_bits = hash_bits;
    p.pow2_bits = pow2_bits;

    const size_t need = (size_t)B * NLEVELS * sizeof(float2);
    const int chunk1 = BLOCK * PPT;
    if (ws_size >= need && (B % chunk1) == 0 && (B % BLOCK) == 0 &&
        ((B / chunk1) & (B / chunk1 - 1)) == 0) {
        int bpl_shift = 0;
        while ((1 << bpl_shift) * chunk1 < B) ++bpl_shift;
        hashenc_pass1<<<dim3(NLEVELS << bpl_shift), dim3(BLOCK), 0, stream>>>(
            xyz, emb, (float2*)d_ws, p, B, bpl_shift);
        hashenc_pass2<<<dim3(B / BLOCK), dim3(BLOCK), 0, stream>>>(
            (const float2*)d_ws, out, B);
    } else {
        hashenc_fwd<<<dim3(B / BLOCK), dim3(BLOCK), 0, stream>>>(xyz, emb, out, p);
    }
}